// Round 8
// baseline (402.468 us; speedup 1.0000x reference)
//
#include <hip/hip_runtime.h>

// CARAFE on MI355X. B=4, C=256, H=W=64, CMID=64, NK=100 (s=2, k=5).
// v5b (v5 + macro-precedence fix: XWRITE's TB now parenthesized; ternary hoisted).
// FULL FUSION: k0a (weight transform) + k123 (conv3x3+relu MFMA -> conv1x1+softmax
//     -> reassembly+pixel-shuffle, all per-bh in one 512-thread block, grid 256).
//     kern never touches global: kts stays in LDS; its 25 f32x4 per thread are
//     chunk-invariant -> hoisted to 100 VGPRs once. Phase-3: 2 halves x 256 thr run the
//     proven k3-v4 inner loop on 2 chunks/iter, double-buffered tiles, T14 load-split.
// LDS map (122112 B):
//   conv  : xs0@0(15872) xs1@15872 wl0@31744(36864) wl1@68608(36864) fs@105472(16640)
//   phase2: red@0(4096, alias xs0), kts@68608(25600, alias wl1 - dead after last MFMA)
//   phase3: tA0@0 tB0@21760 tA1@43520 (dead conv regions), kts@68608..94208,
//           tB1@94208..115968. Tiles 21760 B each: [r5][g4][slotSW68][c4] f32.

#define BB 4
#define CC 256
#define HH 64
#define WW 64
#define CMID 64
#define NKCH 100

typedef __bf16 bf16;
typedef __bf16 bf16x8 __attribute__((ext_vector_type(8)));
typedef float f32x4 __attribute__((ext_vector_type(4)));

__device__ __forceinline__ void async_copy16(const void* gsrc, void* ldst) {
    __builtin_amdgcn_global_load_lds(
        (__attribute__((address_space(1))) void*)(void*)gsrc,
        (__attribute__((address_space(3))) void*)ldst, 16, 0, 0);
}

// ---------------- k0a: w1 [oc][ic][3][3] fp32 -> w1c bf16 [c8][kk][q][oc][8] ----------------
__global__ void k0a_transform(const float* __restrict__ w1, bf16* __restrict__ w1c) {
    int c8 = blockIdx.x;          // 0..7
    int oq = blockIdx.y;          // 0..3
    int tid = threadIdx.x;
    __shared__ __align__(16) float wf[16 * 300];

    for (int i = tid; i < 16 * 72; i += 256) {
        int o = i / 72, r = i % 72;
        *(float4*)&wf[o * 300 + r * 4] =
            *(const float4*)&w1[(size_t)(oq * 16 + o) * 2304 + c8 * 288 + r * 4];
    }
    __syncthreads();

    for (int t = tid; t < 576; t += 256) {
        int o = t & 15, q = (t >> 4) & 3, kk = t >> 6;
        union { bf16 h[8]; uint4 u; } v;
        #pragma unroll
        for (int i8 = 0; i8 < 8; ++i8)
            v.h[i8] = (bf16)wf[o * 300 + (q * 8 + i8) * 9 + kk];
        *(uint4*)&w1c[(size_t)((((c8 * 9 + kk) * 4 + q) * 64) + oq * 16 + o) * 8] = v.u;
    }
}

// ---------------- k123: fused conv3x3+relu + conv1x1+softmax + reassembly ----------------
__global__ __launch_bounds__(512) void k123_fused(const float* __restrict__ x,
        const bf16* __restrict__ w1c, const float* __restrict__ b1,
        const float* __restrict__ w2, const float* __restrict__ b2,
        float* __restrict__ out) {
    int bh = blockIdx.x;
    int b = bh >> 6, h = bh & 63;
    int tid = threadIdx.x;
    int lane = tid & 63, wid = tid >> 6;
    int l15 = lane & 15, quad = lane >> 4;
    int mhalf = wid & 1, nq = wid >> 1;

    __shared__ __align__(16) char smem[122112];
    bf16*  xs0  = (bf16*)smem;
    bf16*  xs1  = (bf16*)(smem + 15872);
    bf16*  wl0  = (bf16*)(smem + 31744);
    bf16*  wl1  = (bf16*)(smem + 68608);
    float* fs   = (float*)(smem + 105472);
    float* kts  = (float*)(smem + 68608);        // alias wl1 (25600 <= 36864)
    float* red  = (float*)smem;                  // alias xs0 (4096)

    const float* xb = x + (size_t)b * (CC * HH * WW);

    // ---- phase 1: conv3x3 (256->64) + relu, 2-phase pipelined MFMA ----
    int ppp[6], rrr[6];
    bool vmask[6];
    #pragma unroll
    for (int j = 0; j < 6; ++j) {
        int task = wid + j * 8;
        ppp[j] = task & 15;
        rrr[j] = task >> 4;
        int hr = h - 1 + rrr[j];
        vmask[j] = (hr >= 0 && hr < HH);
    }

    float fA0[6], fA1[6], fB0[6], fB1[6];
    #define LOADX(C8, F0, F1)                                                    \
        _Pragma("unroll")                                                        \
        for (int j = 0; j < 6; ++j) {                                            \
            if (vmask[j]) {                                                      \
                const float* src = xb + ((size_t)((C8) * 32 + 2 * ppp[j]) * (HH * WW)) \
                                 + (h - 1 + rrr[j]) * WW + lane;                 \
                F0[j] = src[0]; F1[j] = src[HH * WW];                            \
            }                                                                    \
        }
    #define WRITEB(F0, F1, XSDST)                                                \
        _Pragma("unroll")                                                        \
        for (int j = 0; j < 6; ++j) {                                            \
            if (vmask[j]) {                                                      \
                union { bf16 hh[2]; unsigned u; } cv;                            \
                cv.hh[0] = (bf16)F0[j]; cv.hh[1] = (bf16)F1[j];                  \
                *(unsigned*)&(XSDST)[(rrr[j] * 66 + 1 + lane) * 40 + 2 * ppp[j]] = cv.u; \
            }                                                                    \
        }
    #define ACOPY(C8, WDST)                                                      \
        for (int t = wid; t < 36; t += 8)                                        \
            async_copy16(w1c + ((((C8) * 36 + t) << 9) + lane * 8), (void*)&(WDST)[t << 9]);
    #define MFMAS(XSRC, WSRC)                                                    \
        _Pragma("unroll")                                                        \
        for (int kk = 0; kk < 9; ++kk) {                                         \
            int r3 = kk / 3, kw = kk % 3;                                        \
            bf16x8 a0 = *(const bf16x8*)&(WSRC)[((kk * 4 + quad) * 64 + mhalf * 32 + l15) * 8]; \
            bf16x8 a1 = *(const bf16x8*)&(WSRC)[((kk * 4 + quad) * 64 + mhalf * 32 + 16 + l15) * 8]; \
            bf16x8 xv = *(const bf16x8*)&(XSRC)[(r3 * 66 + nq * 16 + l15 + kw) * 40 + quad * 8]; \
            acc0 = __builtin_amdgcn_mfma_f32_16x16x32_bf16(a0, xv, acc0, 0, 0, 0); \
            acc1 = __builtin_amdgcn_mfma_f32_16x16x32_bf16(a1, xv, acc1, 0, 0, 0); \
        }

    for (int i = tid; i < 7936; i += 512) { xs0[i] = (bf16)0.f; xs1[i] = (bf16)0.f; }
    LOADX(0, fA0, fA1)
    ACOPY(0, wl0)
    __syncthreads();
    WRITEB(fA0, fA1, xs0)
    LOADX(1, fB0, fB1)
    __syncthreads();

    f32x4 acc0 = {0.f, 0.f, 0.f, 0.f}, acc1 = {0.f, 0.f, 0.f, 0.f};

    for (int c8 = 0; c8 < 8; c8 += 2) {
        ACOPY(c8 + 1, wl1)
        MFMAS(xs0, wl0)
        WRITEB(fB0, fB1, xs1)
        if (c8 < 6) { LOADX(c8 + 2, fA0, fA1) }
        __syncthreads();
        if (c8 < 6) { ACOPY(c8 + 2, wl0) }
        MFMAS(xs1, wl1)
        if (c8 < 6) { WRITEB(fA0, fA1, xs0) }
        if (c8 < 6) { LOADX(c8 + 3, fB0, fB1) }
        __syncthreads();
    }

    // conv epilogue: bias+relu -> fs (fp32 LDS)
    int px = nq * 16 + l15;
    #pragma unroll
    for (int mi = 0; mi < 2; ++mi) {
        int oc0 = mhalf * 32 + mi * 16 + quad * 4;
        float4 bv = *(const float4*)&b1[oc0];
        f32x4 v = mi ? acc1 : acc0;
        fs[(oc0 + 0) * 65 + px] = fmaxf(v[0] + bv.x, 0.f);
        fs[(oc0 + 1) * 65 + px] = fmaxf(v[1] + bv.y, 0.f);
        fs[(oc0 + 2) * 65 + px] = fmaxf(v[2] + bv.z, 0.f);
        fs[(oc0 + 3) * 65 + px] = fmaxf(v[3] + bv.w, 0.f);
    }
    __syncthreads();

    // ---- phase-3 identities + T14 pre-issue of pair-0 x tiles (hides under phase 2) ----
    int t8 = tid & 255, h2 = tid >> 8;
    int w3 = t8 & 63, cg3 = t8 >> 6;
    #define XLOAD(P, V)                                                          \
        _Pragma("unroll")                                                        \
        for (int k = 0; k < 5; ++k) {                                            \
            int idx = t8 + k * 256;                                              \
            int u = idx & 15, cc = (idx >> 4) & 15, rr = idx >> 8;               \
            int hr = h - 2 + rr;                                                 \
            V[k] = make_float4(0.f, 0.f, 0.f, 0.f);                              \
            if (hr >= 0 && hr < HH)                                              \
                V[k] = *(const float4*)&x[(((size_t)b * CC + (2 * (P) + h2) * 16 + cc) * HH + hr) * WW + 4 * u]; \
        }
    #define XWRITE(V, TB)                                                        \
        _Pragma("unroll")                                                        \
        for (int k = 0; k < 5; ++k) {                                            \
            int idx = t8 + k * 256;                                              \
            int u = idx & 15, cc = (idx >> 4) & 15, rr = idx >> 8;               \
            int bse = (rr * 4 + (cc >> 2)) * 68;                                 \
            int c = cc & 3;                                                      \
            _Pragma("unroll")                                                    \
            for (int j = 0; j < 4; ++j) {                                        \
                int s = 2 + 4 * u + j;                                           \
                int sw = s ^ ((s >> 3) & 7);                                     \
                (TB)[(bse + sw) * 4 + c] = ((const float*)&V[k])[j];             \
            }                                                                    \
        }
    float4 xst[5];
    XLOAD(0, xst)

    // ---- phase 2: conv1x1 (64->100) + softmax over FULL 100-channel dim ----
    int w = lane;
    int g = wid, s2 = g & 3, ihalf = g >> 2;
    int i0 = ihalf ? 13 : 0;

    float4 fv[16];
    #pragma unroll
    for (int q = 0; q < 16; ++q) {
        fv[q].x = fs[(4 * q + 0) * 65 + w];
        fv[q].y = fs[(4 * q + 1) * 65 + w];
        fv[q].z = fs[(4 * q + 2) * 65 + w];
        fv[q].w = fs[(4 * q + 3) * 65 + w];
    }

    float lg[13];
    #pragma unroll
    for (int ii = 0; ii < 13; ++ii) {
        int idx = i0 + ii;
        bool act = (idx < 25);
        int oc = s2 * 25 + (act ? idx : 0);
        float a = b2[oc];
        const float4* wr = (const float4*)&w2[oc * 64];   // wave-uniform, L2-hot
        #pragma unroll
        for (int q = 0; q < 16; ++q) {
            float4 wv = wr[q];
            a += fv[q].x * wv.x + fv[q].y * wv.y + fv[q].z * wv.z + fv[q].w * wv.w;
        }
        lg[ii] = act ? a : -1e30f;
    }

    float m = -1e30f;
    #pragma unroll
    for (int ii = 0; ii < 13; ++ii) m = fmaxf(m, lg[ii]);
    red[g * 64 + w] = m;
    __syncthreads();
    m = fmaxf(fmaxf(fmaxf(red[0 * 64 + w], red[1 * 64 + w]),
                    fmaxf(red[2 * 64 + w], red[3 * 64 + w])),
              fmaxf(fmaxf(red[4 * 64 + w], red[5 * 64 + w]),
                    fmaxf(red[6 * 64 + w], red[7 * 64 + w])));
    float ssum = 0.f;
    #pragma unroll
    for (int ii = 0; ii < 13; ++ii) { lg[ii] = __expf(lg[ii] - m); ssum += lg[ii]; }
    red[512 + g * 64 + w] = ssum;
    __syncthreads();
    ssum = ((red[512 + 0 * 64 + w] + red[512 + 1 * 64 + w]) +
            (red[512 + 2 * 64 + w] + red[512 + 3 * 64 + w])) +
           ((red[512 + 4 * 64 + w] + red[512 + 5 * 64 + w]) +
            (red[512 + 6 * 64 + w] + red[512 + 7 * 64 + w]));
    float inv = 1.f / ssum;
    #pragma unroll
    for (int ii = 0; ii < 13; ++ii)
        if (i0 + ii < 25) kts[((i0 + ii) * 64 + w) * 4 + s2] = lg[ii] * inv;
    __syncthreads();   // kts visible; red/fs/xs/wl regions now dead

    // ---- phase 3: reassembly + pixel shuffle, 2 chunks/iter, double-buffered tiles ----
    // kv is chunk-invariant: hoist 25 f32x4 (100 VGPR), contiguous conflict-free b128
    f32x4 kv[5][5];
    #pragma unroll
    for (int r = 0; r < 5; ++r)
        #pragma unroll
        for (int kw = 0; kw < 5; ++kw)
            kv[r][kw] = *(const f32x4*)&kts[((r * 5 + kw) * 64 + w3) * 4];

    // zero border slots (0,1,66,67) of all 4 tile regions once (never overwritten)
    #pragma unroll
    for (int reg = 0; reg < 4; ++reg) {
        const int tb = (reg == 0) ? 0 : (reg == 1) ? 21760 : (reg == 2) ? 43520 : 94208;
        if (tid < 320) {
            int c = tid & 3, q = (tid >> 2) & 3, rg = tid >> 4;
            int slot = (q < 2) ? q : (q + 64);
            ((float*)(smem + tb))[(rg * 68 + slot) * 4 + c] = 0.f;
        }
    }

    float* tb0 = (float*)(smem + (h2 ? 21760 : 0));
    float* tb1 = (float*)(smem + (h2 ? 94208 : 43520));

    int swk[5];
    #pragma unroll
    for (int kw = 0; kw < 5; ++kw) {
        int s = w3 + kw;
        swk[kw] = s ^ ((s >> 3) & 7);
    }

    XWRITE(xst, tb0)          // pair-0 tile (loads issued before phase 2)
    __syncthreads();

    for (int p = 0; p < 8; ++p) {
        if (p < 7) { XLOAD(p + 1, xst) }       // T14: issue next pair's loads now
        float* T = (p & 1) ? tb1 : tb0;
        f32x4 a0 = {0.f,0.f,0.f,0.f}, a1 = {0.f,0.f,0.f,0.f};
        f32x4 a2 = {0.f,0.f,0.f,0.f}, a3 = {0.f,0.f,0.f,0.f};
        #pragma unroll
        for (int r = 0; r < 5; ++r) {
            #pragma unroll
            for (int kw = 0; kw < 5; ++kw) {
                f32x4 kvv = kv[r][kw];
                f32x4 xv = *(const f32x4*)&T[((r * 4 + cg3) * 68 + swk[kw]) * 4];
                a0 += kvv.x * xv;
                a1 += kvv.y * xv;
                a2 += kvv.z * xv;
                a3 += kvv.w * xv;
            }
        }
        int cq = (2 * p + h2) * 4 + cg3;
        f32x4 accs[4] = {a0, a1, a2, a3};
        #pragma unroll
        for (int s = 0; s < 4; ++s) {
            size_t base = (((size_t)b * 256 + s * 64 + cq) * 128 + 2 * h) * 128 + 2 * w3;
            *(float2*)&out[base]       = make_float2(accs[s][0], accs[s][1]);
            *(float2*)&out[base + 128] = make_float2(accs[s][2], accs[s][3]);
        }
        if (p < 7) {
            float* Tnext = (p & 1) ? tb0 : tb1;
            XWRITE(xst, Tnext)
        }
        __syncthreads();
    }
    #undef LOADX
    #undef WRITEB
    #undef ACOPY
    #undef MFMAS
    #undef XLOAD
    #undef XWRITE
}

extern "C" void kernel_launch(void* const* d_in, const int* in_sizes, int n_in,
                              void* d_out, int out_size, void* d_ws, size_t ws_size,
                              hipStream_t stream) {
    const float* x  = (const float*)d_in[0];
    const float* w1 = (const float*)d_in[1];
    const float* b1 = (const float*)d_in[2];
    const float* w2 = (const float*)d_in[3];
    const float* b2 = (const float*)d_in[4];
    float* out = (float*)d_out;

    bf16* w1c = (bf16*)d_ws;                     // 294,912 B

    k0a_transform<<<dim3(8, 4), 256, 0, stream>>>(w1, w1c);
    k123_fused<<<dim3(BB * HH), 512, 0, stream>>>(x, w1c, b1, w2, b2, out);
}

// Round 9
// 398.465 us; speedup vs baseline: 1.0100x; 1.0100x over previous
//
#include <hip/hip_runtime.h>

// CARAFE on MI355X. B=4, C=256, H=W=64, CMID=64, NK=100 (s=2, k=5).
// v6 = v5b + __launch_bounds__(512, 2) on k123_fused.
//   v5b's plain __launch_bounds__(512) let the allocator cap at 128 VGPRs (targeting
//   4 waves/SIMD) while the 122 KB LDS already limits to 1 block/CU (= 2 waves/SIMD).
//   kv[5][5] (100 regs) + xst (20) spilled to scratch: +670 MB HBM traffic, 3x slowdown
//   (FETCH 546 MB vs ~33 MB expected). (512,2) permits 256 VGPR/wave -> no spill.
// FULL FUSION: k0a (weight transform) + k123 (conv3x3+relu MFMA -> conv1x1+softmax
//     -> reassembly+pixel-shuffle, all per-bh in one 512-thread block, grid 256).
//     kern never touches global: kts stays in LDS; its 25 f32x4 per thread are
//     chunk-invariant -> hoisted to 100 VGPRs once. Phase-3: 2 halves x 256 thr,
//     2 chunks/iter, double-buffered tiles, T14 load-split.
// LDS map (122112 B):
//   conv  : xs0@0(15872) xs1@15872 wl0@31744(36864) wl1@68608(36864) fs@105472(16640)
//   phase2: red@0(4096, alias xs0), kts@68608(25600, alias wl1 - dead after last MFMA)
//   phase3: tA0@0 tB0@21760 tA1@43520 (dead conv regions), kts@68608..94208,
//           tB1@94208..115968. Tiles 21760 B each: [r5][g4][slotSW68][c4] f32.

#define BB 4
#define CC 256
#define HH 64
#define WW 64
#define CMID 64
#define NKCH 100

typedef __bf16 bf16;
typedef __bf16 bf16x8 __attribute__((ext_vector_type(8)));
typedef float f32x4 __attribute__((ext_vector_type(4)));

__device__ __forceinline__ void async_copy16(const void* gsrc, void* ldst) {
    __builtin_amdgcn_global_load_lds(
        (__attribute__((address_space(1))) void*)(void*)gsrc,
        (__attribute__((address_space(3))) void*)ldst, 16, 0, 0);
}

// ---------------- k0a: w1 [oc][ic][3][3] fp32 -> w1c bf16 [c8][kk][q][oc][8] ----------------
__global__ void k0a_transform(const float* __restrict__ w1, bf16* __restrict__ w1c) {
    int c8 = blockIdx.x;          // 0..7
    int oq = blockIdx.y;          // 0..3
    int tid = threadIdx.x;
    __shared__ __align__(16) float wf[16 * 300];

    for (int i = tid; i < 16 * 72; i += 256) {
        int o = i / 72, r = i % 72;
        *(float4*)&wf[o * 300 + r * 4] =
            *(const float4*)&w1[(size_t)(oq * 16 + o) * 2304 + c8 * 288 + r * 4];
    }
    __syncthreads();

    for (int t = tid; t < 576; t += 256) {
        int o = t & 15, q = (t >> 4) & 3, kk = t >> 6;
        union { bf16 h[8]; uint4 u; } v;
        #pragma unroll
        for (int i8 = 0; i8 < 8; ++i8)
            v.h[i8] = (bf16)wf[o * 300 + (q * 8 + i8) * 9 + kk];
        *(uint4*)&w1c[(size_t)((((c8 * 9 + kk) * 4 + q) * 64) + oq * 16 + o) * 8] = v.u;
    }
}

// ---------------- k123: fused conv3x3+relu + conv1x1+softmax + reassembly ----------------
__global__ __launch_bounds__(512, 2) void k123_fused(const float* __restrict__ x,
        const bf16* __restrict__ w1c, const float* __restrict__ b1,
        const float* __restrict__ w2, const float* __restrict__ b2,
        float* __restrict__ out) {
    int bh = blockIdx.x;
    int b = bh >> 6, h = bh & 63;
    int tid = threadIdx.x;
    int lane = tid & 63, wid = tid >> 6;
    int l15 = lane & 15, quad = lane >> 4;
    int mhalf = wid & 1, nq = wid >> 1;

    __shared__ __align__(16) char smem[122112];
    bf16*  xs0  = (bf16*)smem;
    bf16*  xs1  = (bf16*)(smem + 15872);
    bf16*  wl0  = (bf16*)(smem + 31744);
    bf16*  wl1  = (bf16*)(smem + 68608);
    float* fs   = (float*)(smem + 105472);
    float* kts  = (float*)(smem + 68608);        // alias wl1 (25600 <= 36864)
    float* red  = (float*)smem;                  // alias xs0 (4096)

    const float* xb = x + (size_t)b * (CC * HH * WW);

    // ---- phase 1: conv3x3 (256->64) + relu, 2-phase pipelined MFMA ----
    int ppp[6], rrr[6];
    bool vmask[6];
    #pragma unroll
    for (int j = 0; j < 6; ++j) {
        int task = wid + j * 8;
        ppp[j] = task & 15;
        rrr[j] = task >> 4;
        int hr = h - 1 + rrr[j];
        vmask[j] = (hr >= 0 && hr < HH);
    }

    float fA0[6], fA1[6], fB0[6], fB1[6];
    #define LOADX(C8, F0, F1)                                                    \
        _Pragma("unroll")                                                        \
        for (int j = 0; j < 6; ++j) {                                            \
            if (vmask[j]) {                                                      \
                const float* src = xb + ((size_t)((C8) * 32 + 2 * ppp[j]) * (HH * WW)) \
                                 + (h - 1 + rrr[j]) * WW + lane;                 \
                F0[j] = src[0]; F1[j] = src[HH * WW];                            \
            }                                                                    \
        }
    #define WRITEB(F0, F1, XSDST)                                                \
        _Pragma("unroll")                                                        \
        for (int j = 0; j < 6; ++j) {                                            \
            if (vmask[j]) {                                                      \
                union { bf16 hh[2]; unsigned u; } cv;                            \
                cv.hh[0] = (bf16)F0[j]; cv.hh[1] = (bf16)F1[j];                  \
                *(unsigned*)&(XSDST)[(rrr[j] * 66 + 1 + lane) * 40 + 2 * ppp[j]] = cv.u; \
            }                                                                    \
        }
    #define ACOPY(C8, WDST)                                                      \
        for (int t = wid; t < 36; t += 8)                                        \
            async_copy16(w1c + ((((C8) * 36 + t) << 9) + lane * 8), (void*)&(WDST)[t << 9]);
    #define MFMAS(XSRC, WSRC)                                                    \
        _Pragma("unroll")                                                        \
        for (int kk = 0; kk < 9; ++kk) {                                         \
            int r3 = kk / 3, kw = kk % 3;                                        \
            bf16x8 a0 = *(const bf16x8*)&(WSRC)[((kk * 4 + quad) * 64 + mhalf * 32 + l15) * 8]; \
            bf16x8 a1 = *(const bf16x8*)&(WSRC)[((kk * 4 + quad) * 64 + mhalf * 32 + 16 + l15) * 8]; \
            bf16x8 xv = *(const bf16x8*)&(XSRC)[(r3 * 66 + nq * 16 + l15 + kw) * 40 + quad * 8]; \
            acc0 = __builtin_amdgcn_mfma_f32_16x16x32_bf16(a0, xv, acc0, 0, 0, 0); \
            acc1 = __builtin_amdgcn_mfma_f32_16x16x32_bf16(a1, xv, acc1, 0, 0, 0); \
        }

    for (int i = tid; i < 7936; i += 512) { xs0[i] = (bf16)0.f; xs1[i] = (bf16)0.f; }
    LOADX(0, fA0, fA1)
    ACOPY(0, wl0)
    __syncthreads();
    WRITEB(fA0, fA1, xs0)
    LOADX(1, fB0, fB1)
    __syncthreads();

    f32x4 acc0 = {0.f, 0.f, 0.f, 0.f}, acc1 = {0.f, 0.f, 0.f, 0.f};

    for (int c8 = 0; c8 < 8; c8 += 2) {
        ACOPY(c8 + 1, wl1)
        MFMAS(xs0, wl0)
        WRITEB(fB0, fB1, xs1)
        if (c8 < 6) { LOADX(c8 + 2, fA0, fA1) }
        __syncthreads();
        if (c8 < 6) { ACOPY(c8 + 2, wl0) }
        MFMAS(xs1, wl1)
        if (c8 < 6) { WRITEB(fA0, fA1, xs0) }
        if (c8 < 6) { LOADX(c8 + 3, fB0, fB1) }
        __syncthreads();
    }

    // conv epilogue: bias+relu -> fs (fp32 LDS)
    int px = nq * 16 + l15;
    #pragma unroll
    for (int mi = 0; mi < 2; ++mi) {
        int oc0 = mhalf * 32 + mi * 16 + quad * 4;
        float4 bv = *(const float4*)&b1[oc0];
        f32x4 v = mi ? acc1 : acc0;
        fs[(oc0 + 0) * 65 + px] = fmaxf(v[0] + bv.x, 0.f);
        fs[(oc0 + 1) * 65 + px] = fmaxf(v[1] + bv.y, 0.f);
        fs[(oc0 + 2) * 65 + px] = fmaxf(v[2] + bv.z, 0.f);
        fs[(oc0 + 3) * 65 + px] = fmaxf(v[3] + bv.w, 0.f);
    }
    __syncthreads();

    // ---- phase-3 identities + T14 pre-issue of pair-0 x tiles (hides under phase 2) ----
    int t8 = tid & 255, h2 = tid >> 8;
    int w3 = t8 & 63, cg3 = t8 >> 6;
    #define XLOAD(P, V)                                                          \
        _Pragma("unroll")                                                        \
        for (int k = 0; k < 5; ++k) {                                            \
            int idx = t8 + k * 256;                                              \
            int u = idx & 15, cc = (idx >> 4) & 15, rr = idx >> 8;               \
            int hr = h - 2 + rr;                                                 \
            V[k] = make_float4(0.f, 0.f, 0.f, 0.f);                              \
            if (hr >= 0 && hr < HH)                                              \
                V[k] = *(const float4*)&x[(((size_t)b * CC + (2 * (P) + h2) * 16 + cc) * HH + hr) * WW + 4 * u]; \
        }
    #define XWRITE(V, TB)                                                        \
        _Pragma("unroll")                                                        \
        for (int k = 0; k < 5; ++k) {                                            \
            int idx = t8 + k * 256;                                              \
            int u = idx & 15, cc = (idx >> 4) & 15, rr = idx >> 8;               \
            int bse = (rr * 4 + (cc >> 2)) * 68;                                 \
            int c = cc & 3;                                                      \
            _Pragma("unroll")                                                    \
            for (int j = 0; j < 4; ++j) {                                        \
                int s = 2 + 4 * u + j;                                           \
                int sw = s ^ ((s >> 3) & 7);                                     \
                (TB)[(bse + sw) * 4 + c] = ((const float*)&V[k])[j];             \
            }                                                                    \
        }
    float4 xst[5];
    XLOAD(0, xst)

    // ---- phase 2: conv1x1 (64->100) + softmax over FULL 100-channel dim ----
    int w = lane;
    int g = wid, s2 = g & 3, ihalf = g >> 2;
    int i0 = ihalf ? 13 : 0;

    float4 fv[16];
    #pragma unroll
    for (int q = 0; q < 16; ++q) {
        fv[q].x = fs[(4 * q + 0) * 65 + w];
        fv[q].y = fs[(4 * q + 1) * 65 + w];
        fv[q].z = fs[(4 * q + 2) * 65 + w];
        fv[q].w = fs[(4 * q + 3) * 65 + w];
    }

    float lg[13];
    #pragma unroll
    for (int ii = 0; ii < 13; ++ii) {
        int idx = i0 + ii;
        bool act = (idx < 25);
        int oc = s2 * 25 + (act ? idx : 0);
        float a = b2[oc];
        const float4* wr = (const float4*)&w2[oc * 64];   // wave-uniform, L2-hot
        #pragma unroll
        for (int q = 0; q < 16; ++q) {
            float4 wv = wr[q];
            a += fv[q].x * wv.x + fv[q].y * wv.y + fv[q].z * wv.z + fv[q].w * wv.w;
        }
        lg[ii] = act ? a : -1e30f;
    }

    float m = -1e30f;
    #pragma unroll
    for (int ii = 0; ii < 13; ++ii) m = fmaxf(m, lg[ii]);
    red[g * 64 + w] = m;
    __syncthreads();
    m = fmaxf(fmaxf(fmaxf(red[0 * 64 + w], red[1 * 64 + w]),
                    fmaxf(red[2 * 64 + w], red[3 * 64 + w])),
              fmaxf(fmaxf(red[4 * 64 + w], red[5 * 64 + w]),
                    fmaxf(red[6 * 64 + w], red[7 * 64 + w])));
    float ssum = 0.f;
    #pragma unroll
    for (int ii = 0; ii < 13; ++ii) { lg[ii] = __expf(lg[ii] - m); ssum += lg[ii]; }
    red[512 + g * 64 + w] = ssum;
    __syncthreads();
    ssum = ((red[512 + 0 * 64 + w] + red[512 + 1 * 64 + w]) +
            (red[512 + 2 * 64 + w] + red[512 + 3 * 64 + w])) +
           ((red[512 + 4 * 64 + w] + red[512 + 5 * 64 + w]) +
            (red[512 + 6 * 64 + w] + red[512 + 7 * 64 + w]));
    float inv = 1.f / ssum;
    #pragma unroll
    for (int ii = 0; ii < 13; ++ii)
        if (i0 + ii < 25) kts[((i0 + ii) * 64 + w) * 4 + s2] = lg[ii] * inv;
    __syncthreads();   // kts visible; red/fs/xs/wl regions now dead

    // ---- phase 3: reassembly + pixel shuffle, 2 chunks/iter, double-buffered tiles ----
    // kv is chunk-invariant: hoist 25 f32x4 (100 VGPR), contiguous conflict-free b128
    f32x4 kv[5][5];
    #pragma unroll
    for (int r = 0; r < 5; ++r)
        #pragma unroll
        for (int kw = 0; kw < 5; ++kw)
            kv[r][kw] = *(const f32x4*)&kts[((r * 5 + kw) * 64 + w3) * 4];

    // zero border slots (0,1,66,67) of all 4 tile regions once (never overwritten)
    #pragma unroll
    for (int reg = 0; reg < 4; ++reg) {
        const int tb = (reg == 0) ? 0 : (reg == 1) ? 21760 : (reg == 2) ? 43520 : 94208;
        if (tid < 320) {
            int c = tid & 3, q = (tid >> 2) & 3, rg = tid >> 4;
            int slot = (q < 2) ? q : (q + 64);
            ((float*)(smem + tb))[(rg * 68 + slot) * 4 + c] = 0.f;
        }
    }

    float* tb0 = (float*)(smem + (h2 ? 21760 : 0));
    float* tb1 = (float*)(smem + (h2 ? 94208 : 43520));

    int swk[5];
    #pragma unroll
    for (int kw = 0; kw < 5; ++kw) {
        int s = w3 + kw;
        swk[kw] = s ^ ((s >> 3) & 7);
    }

    XWRITE(xst, tb0)          // pair-0 tile (loads issued before phase 2)
    __syncthreads();

    for (int p = 0; p < 8; ++p) {
        if (p < 7) { XLOAD(p + 1, xst) }       // T14: issue next pair's loads now
        float* T = (p & 1) ? tb1 : tb0;
        f32x4 a0 = {0.f,0.f,0.f,0.f}, a1 = {0.f,0.f,0.f,0.f};
        f32x4 a2 = {0.f,0.f,0.f,0.f}, a3 = {0.f,0.f,0.f,0.f};
        #pragma unroll
        for (int r = 0; r < 5; ++r) {
            #pragma unroll
            for (int kw = 0; kw < 5; ++kw) {
                f32x4 kvv = kv[r][kw];
                f32x4 xv = *(const f32x4*)&T[((r * 4 + cg3) * 68 + swk[kw]) * 4];
                a0 += kvv.x * xv;
                a1 += kvv.y * xv;
                a2 += kvv.z * xv;
                a3 += kvv.w * xv;
            }
        }
        int cq = (2 * p + h2) * 4 + cg3;
        f32x4 accs[4] = {a0, a1, a2, a3};
        #pragma unroll
        for (int s = 0; s < 4; ++s) {
            size_t base = (((size_t)b * 256 + s * 64 + cq) * 128 + 2 * h) * 128 + 2 * w3;
            *(float2*)&out[base]       = make_float2(accs[s][0], accs[s][1]);
            *(float2*)&out[base + 128] = make_float2(accs[s][2], accs[s][3]);
        }
        if (p < 7) {
            float* Tnext = (p & 1) ? tb0 : tb1;
            XWRITE(xst, Tnext)
        }
        __syncthreads();
    }
    #undef LOADX
    #undef WRITEB
    #undef ACOPY
    #undef MFMAS
    #undef XLOAD
    #undef XWRITE
}

extern "C" void kernel_launch(void* const* d_in, const int* in_sizes, int n_in,
                              void* d_out, int out_size, void* d_ws, size_t ws_size,
                              hipStream_t stream) {
    const float* x  = (const float*)d_in[0];
    const float* w1 = (const float*)d_in[1];
    const float* b1 = (const float*)d_in[2];
    const float* w2 = (const float*)d_in[3];
    const float* b2 = (const float*)d_in[4];
    float* out = (float*)d_out;

    bf16* w1c = (bf16*)d_ws;                     // 294,912 B

    k0a_transform<<<dim3(8, 4), 256, 0, stream>>>(w1, w1c);
    k123_fused<<<dim3(BB * HH), 512, 0, stream>>>(x, w1c, b1, w2, b2, out);
}

// Round 10
// 129.890 us; speedup vs baseline: 3.0985x; 3.0677x over previous
//
#include <hip/hip_runtime.h>

// CARAFE on MI355X. B=4, C=256, H=W=64, CMID=64, NK=100 (s=2, k=5).
// v7 = v6 minus the kv[5][5] register hoist.
//   Rounds 8/9 showed the allocator pins this kernel at 128 VGPRs (launch_bounds(512,2)
//   did NOT lift it) and spills kv+xst to scratch: +500 MB HBM round-trip (FETCH 546 MB,
//   WRITE 187 MB), 3x slowdown. Fix: read the 25 chunk-invariant kern f32x4 from kts
//   (LDS) inside the p-loop instead of hoisting -> live regs ~80, no spill. kts reads
//   are lane-contiguous b128, ~1.6 MB/block vs 69 TB/s LDS ceiling: noise.
// FULL FUSION: k0a (weight transform) + k123 (conv3x3+relu MFMA -> conv1x1+softmax
//     -> reassembly+pixel-shuffle, per-bh 512-thread block, grid 256). kern never
//     touches global. Phase-3: 2 halves x 256 thr, 2 chunks/iter, dbuf tiles, T14.
// LDS map (122112 B):
//   conv  : xs0@0(15872) xs1@15872 wl0@31744(36864) wl1@68608(36864) fs@105472(16640)
//   phase2: red@0(4096, alias xs0), kts@68608(25600, alias wl1 - dead after last MFMA)
//   phase3: tA0@0 tB0@21760 tA1@43520 (dead conv regions), kts@68608..94208,
//           tB1@94208..115968. Tiles 21760 B each: [r5][g4][slotSW68][c4] f32.

#define BB 4
#define CC 256
#define HH 64
#define WW 64
#define CMID 64
#define NKCH 100

typedef __bf16 bf16;
typedef __bf16 bf16x8 __attribute__((ext_vector_type(8)));
typedef float f32x4 __attribute__((ext_vector_type(4)));

__device__ __forceinline__ void async_copy16(const void* gsrc, void* ldst) {
    __builtin_amdgcn_global_load_lds(
        (__attribute__((address_space(1))) void*)(void*)gsrc,
        (__attribute__((address_space(3))) void*)ldst, 16, 0, 0);
}

// ---------------- k0a: w1 [oc][ic][3][3] fp32 -> w1c bf16 [c8][kk][q][oc][8] ----------------
__global__ void k0a_transform(const float* __restrict__ w1, bf16* __restrict__ w1c) {
    int c8 = blockIdx.x;          // 0..7
    int oq = blockIdx.y;          // 0..3
    int tid = threadIdx.x;
    __shared__ __align__(16) float wf[16 * 300];

    for (int i = tid; i < 16 * 72; i += 256) {
        int o = i / 72, r = i % 72;
        *(float4*)&wf[o * 300 + r * 4] =
            *(const float4*)&w1[(size_t)(oq * 16 + o) * 2304 + c8 * 288 + r * 4];
    }
    __syncthreads();

    for (int t = tid; t < 576; t += 256) {
        int o = t & 15, q = (t >> 4) & 3, kk = t >> 6;
        union { bf16 h[8]; uint4 u; } v;
        #pragma unroll
        for (int i8 = 0; i8 < 8; ++i8)
            v.h[i8] = (bf16)wf[o * 300 + (q * 8 + i8) * 9 + kk];
        *(uint4*)&w1c[(size_t)((((c8 * 9 + kk) * 4 + q) * 64) + oq * 16 + o) * 8] = v.u;
    }
}

// ---------------- k123: fused conv3x3+relu + conv1x1+softmax + reassembly ----------------
__global__ __launch_bounds__(512) void k123_fused(const float* __restrict__ x,
        const bf16* __restrict__ w1c, const float* __restrict__ b1,
        const float* __restrict__ w2, const float* __restrict__ b2,
        float* __restrict__ out) {
    int bh = blockIdx.x;
    int b = bh >> 6, h = bh & 63;
    int tid = threadIdx.x;
    int lane = tid & 63, wid = tid >> 6;
    int l15 = lane & 15, quad = lane >> 4;
    int mhalf = wid & 1, nq = wid >> 1;

    __shared__ __align__(16) char smem[122112];
    bf16*  xs0  = (bf16*)smem;
    bf16*  xs1  = (bf16*)(smem + 15872);
    bf16*  wl0  = (bf16*)(smem + 31744);
    bf16*  wl1  = (bf16*)(smem + 68608);
    float* fs   = (float*)(smem + 105472);
    float* kts  = (float*)(smem + 68608);        // alias wl1 (25600 <= 36864)
    float* red  = (float*)smem;                  // alias xs0 (4096)

    const float* xb = x + (size_t)b * (CC * HH * WW);

    // ---- phase 1: conv3x3 (256->64) + relu, 2-phase pipelined MFMA ----
    int ppp[6], rrr[6];
    bool vmask[6];
    #pragma unroll
    for (int j = 0; j < 6; ++j) {
        int task = wid + j * 8;
        ppp[j] = task & 15;
        rrr[j] = task >> 4;
        int hr = h - 1 + rrr[j];
        vmask[j] = (hr >= 0 && hr < HH);
    }

    float fA0[6], fA1[6], fB0[6], fB1[6];
    #define LOADX(C8, F0, F1)                                                    \
        _Pragma("unroll")                                                        \
        for (int j = 0; j < 6; ++j) {                                            \
            if (vmask[j]) {                                                      \
                const float* src = xb + ((size_t)((C8) * 32 + 2 * ppp[j]) * (HH * WW)) \
                                 + (h - 1 + rrr[j]) * WW + lane;                 \
                F0[j] = src[0]; F1[j] = src[HH * WW];                            \
            }                                                                    \
        }
    #define WRITEB(F0, F1, XSDST)                                                \
        _Pragma("unroll")                                                        \
        for (int j = 0; j < 6; ++j) {                                            \
            if (vmask[j]) {                                                      \
                union { bf16 hh[2]; unsigned u; } cv;                            \
                cv.hh[0] = (bf16)F0[j]; cv.hh[1] = (bf16)F1[j];                  \
                *(unsigned*)&(XSDST)[(rrr[j] * 66 + 1 + lane) * 40 + 2 * ppp[j]] = cv.u; \
            }                                                                    \
        }
    #define ACOPY(C8, WDST)                                                      \
        for (int t = wid; t < 36; t += 8)                                        \
            async_copy16(w1c + ((((C8) * 36 + t) << 9) + lane * 8), (void*)&(WDST)[t << 9]);
    #define MFMAS(XSRC, WSRC)                                                    \
        _Pragma("unroll")                                                        \
        for (int kk = 0; kk < 9; ++kk) {                                         \
            int r3 = kk / 3, kw = kk % 3;                                        \
            bf16x8 a0 = *(const bf16x8*)&(WSRC)[((kk * 4 + quad) * 64 + mhalf * 32 + l15) * 8]; \
            bf16x8 a1 = *(const bf16x8*)&(WSRC)[((kk * 4 + quad) * 64 + mhalf * 32 + 16 + l15) * 8]; \
            bf16x8 xv = *(const bf16x8*)&(XSRC)[(r3 * 66 + nq * 16 + l15 + kw) * 40 + quad * 8]; \
            acc0 = __builtin_amdgcn_mfma_f32_16x16x32_bf16(a0, xv, acc0, 0, 0, 0); \
            acc1 = __builtin_amdgcn_mfma_f32_16x16x32_bf16(a1, xv, acc1, 0, 0, 0); \
        }

    for (int i = tid; i < 7936; i += 512) { xs0[i] = (bf16)0.f; xs1[i] = (bf16)0.f; }
    LOADX(0, fA0, fA1)
    ACOPY(0, wl0)
    __syncthreads();
    WRITEB(fA0, fA1, xs0)
    LOADX(1, fB0, fB1)
    __syncthreads();

    f32x4 acc0 = {0.f, 0.f, 0.f, 0.f}, acc1 = {0.f, 0.f, 0.f, 0.f};

    for (int c8 = 0; c8 < 8; c8 += 2) {
        ACOPY(c8 + 1, wl1)
        MFMAS(xs0, wl0)
        WRITEB(fB0, fB1, xs1)
        if (c8 < 6) { LOADX(c8 + 2, fA0, fA1) }
        __syncthreads();
        if (c8 < 6) { ACOPY(c8 + 2, wl0) }
        MFMAS(xs1, wl1)
        if (c8 < 6) { WRITEB(fA0, fA1, xs0) }
        if (c8 < 6) { LOADX(c8 + 3, fB0, fB1) }
        __syncthreads();
    }

    // conv epilogue: bias+relu -> fs (fp32 LDS)
    int px = nq * 16 + l15;
    #pragma unroll
    for (int mi = 0; mi < 2; ++mi) {
        int oc0 = mhalf * 32 + mi * 16 + quad * 4;
        float4 bv = *(const float4*)&b1[oc0];
        f32x4 v = mi ? acc1 : acc0;
        fs[(oc0 + 0) * 65 + px] = fmaxf(v[0] + bv.x, 0.f);
        fs[(oc0 + 1) * 65 + px] = fmaxf(v[1] + bv.y, 0.f);
        fs[(oc0 + 2) * 65 + px] = fmaxf(v[2] + bv.z, 0.f);
        fs[(oc0 + 3) * 65 + px] = fmaxf(v[3] + bv.w, 0.f);
    }
    __syncthreads();

    // ---- phase-3 identities + T14 pre-issue of pair-0 x tiles (hides under phase 2) ----
    int t8 = tid & 255, h2 = tid >> 8;
    int w3 = t8 & 63, cg3 = t8 >> 6;
    #define XLOAD(P, V)                                                          \
        _Pragma("unroll")                                                        \
        for (int k = 0; k < 5; ++k) {                                            \
            int idx = t8 + k * 256;                                              \
            int u = idx & 15, cc = (idx >> 4) & 15, rr = idx >> 8;               \
            int hr = h - 2 + rr;                                                 \
            V[k] = make_float4(0.f, 0.f, 0.f, 0.f);                              \
            if (hr >= 0 && hr < HH)                                              \
                V[k] = *(const float4*)&x[(((size_t)b * CC + (2 * (P) + h2) * 16 + cc) * HH + hr) * WW + 4 * u]; \
        }
    #define XWRITE(V, TB)                                                        \
        _Pragma("unroll")                                                        \
        for (int k = 0; k < 5; ++k) {                                            \
            int idx = t8 + k * 256;                                              \
            int u = idx & 15, cc = (idx >> 4) & 15, rr = idx >> 8;               \
            int bse = (rr * 4 + (cc >> 2)) * 68;                                 \
            int c = cc & 3;                                                      \
            _Pragma("unroll")                                                    \
            for (int j = 0; j < 4; ++j) {                                        \
                int s = 2 + 4 * u + j;                                           \
                int sw = s ^ ((s >> 3) & 7);                                     \
                (TB)[(bse + sw) * 4 + c] = ((const float*)&V[k])[j];             \
            }                                                                    \
        }
    float4 xst[5];
    XLOAD(0, xst)

    // ---- phase 2: conv1x1 (64->100) + softmax over FULL 100-channel dim ----
    int w = lane;
    int g = wid, s2 = g & 3, ihalf = g >> 2;
    int i0 = ihalf ? 13 : 0;

    float4 fv[16];
    #pragma unroll
    for (int q = 0; q < 16; ++q) {
        fv[q].x = fs[(4 * q + 0) * 65 + w];
        fv[q].y = fs[(4 * q + 1) * 65 + w];
        fv[q].z = fs[(4 * q + 2) * 65 + w];
        fv[q].w = fs[(4 * q + 3) * 65 + w];
    }

    float lg[13];
    #pragma unroll
    for (int ii = 0; ii < 13; ++ii) {
        int idx = i0 + ii;
        bool act = (idx < 25);
        int oc = s2 * 25 + (act ? idx : 0);
        float a = b2[oc];
        const float4* wr = (const float4*)&w2[oc * 64];   // wave-uniform, L2-hot
        #pragma unroll
        for (int q = 0; q < 16; ++q) {
            float4 wv = wr[q];
            a += fv[q].x * wv.x + fv[q].y * wv.y + fv[q].z * wv.z + fv[q].w * wv.w;
        }
        lg[ii] = act ? a : -1e30f;
    }

    float m = -1e30f;
    #pragma unroll
    for (int ii = 0; ii < 13; ++ii) m = fmaxf(m, lg[ii]);
    red[g * 64 + w] = m;
    __syncthreads();
    m = fmaxf(fmaxf(fmaxf(red[0 * 64 + w], red[1 * 64 + w]),
                    fmaxf(red[2 * 64 + w], red[3 * 64 + w])),
              fmaxf(fmaxf(red[4 * 64 + w], red[5 * 64 + w]),
                    fmaxf(red[6 * 64 + w], red[7 * 64 + w])));
    float ssum = 0.f;
    #pragma unroll
    for (int ii = 0; ii < 13; ++ii) { lg[ii] = __expf(lg[ii] - m); ssum += lg[ii]; }
    red[512 + g * 64 + w] = ssum;
    __syncthreads();
    ssum = ((red[512 + 0 * 64 + w] + red[512 + 1 * 64 + w]) +
            (red[512 + 2 * 64 + w] + red[512 + 3 * 64 + w])) +
           ((red[512 + 4 * 64 + w] + red[512 + 5 * 64 + w]) +
            (red[512 + 6 * 64 + w] + red[512 + 7 * 64 + w]));
    float inv = 1.f / ssum;
    #pragma unroll
    for (int ii = 0; ii < 13; ++ii)
        if (i0 + ii < 25) kts[((i0 + ii) * 64 + w) * 4 + s2] = lg[ii] * inv;
    __syncthreads();   // kts visible; red/fs/xs/wl regions now dead

    // ---- phase 3: reassembly + pixel shuffle, 2 chunks/iter, double-buffered tiles ----
    // kv read from kts (LDS) inside the loop: lane-contiguous b128, no register hoist.

    // zero border slots (0,1,66,67) of all 4 tile regions once (never overwritten)
    #pragma unroll
    for (int reg = 0; reg < 4; ++reg) {
        const int tb = (reg == 0) ? 0 : (reg == 1) ? 21760 : (reg == 2) ? 43520 : 94208;
        if (tid < 320) {
            int c = tid & 3, q = (tid >> 2) & 3, rg = tid >> 4;
            int slot = (q < 2) ? q : (q + 64);
            ((float*)(smem + tb))[(rg * 68 + slot) * 4 + c] = 0.f;
        }
    }

    float* tb0 = (float*)(smem + (h2 ? 21760 : 0));
    float* tb1 = (float*)(smem + (h2 ? 94208 : 43520));

    int swk[5];
    #pragma unroll
    for (int kw = 0; kw < 5; ++kw) {
        int s = w3 + kw;
        swk[kw] = s ^ ((s >> 3) & 7);
    }

    XWRITE(xst, tb0)          // pair-0 tile (loads issued before phase 2)
    __syncthreads();

    for (int p = 0; p < 8; ++p) {
        if (p < 7) { XLOAD(p + 1, xst) }       // T14: issue next pair's loads now
        float* T = (p & 1) ? tb1 : tb0;
        f32x4 a0 = {0.f,0.f,0.f,0.f}, a1 = {0.f,0.f,0.f,0.f};
        f32x4 a2 = {0.f,0.f,0.f,0.f}, a3 = {0.f,0.f,0.f,0.f};
        #pragma unroll
        for (int r = 0; r < 5; ++r) {
            #pragma unroll
            for (int kw = 0; kw < 5; ++kw) {
                f32x4 kvv = *(const f32x4*)&kts[((r * 5 + kw) * 64 + w3) * 4];
                f32x4 xv = *(const f32x4*)&T[((r * 4 + cg3) * 68 + swk[kw]) * 4];
                a0 += kvv.x * xv;
                a1 += kvv.y * xv;
                a2 += kvv.z * xv;
                a3 += kvv.w * xv;
            }
        }
        int cq = (2 * p + h2) * 4 + cg3;
        f32x4 accs[4] = {a0, a1, a2, a3};
        #pragma unroll
        for (int s = 0; s < 4; ++s) {
            size_t base = (((size_t)b * 256 + s * 64 + cq) * 128 + 2 * h) * 128 + 2 * w3;
            *(float2*)&out[base]       = make_float2(accs[s][0], accs[s][1]);
            *(float2*)&out[base + 128] = make_float2(accs[s][2], accs[s][3]);
        }
        if (p < 7) {
            float* Tnext = (p & 1) ? tb0 : tb1;
            XWRITE(xst, Tnext)
        }
        __syncthreads();
    }
    #undef LOADX
    #undef WRITEB
    #undef ACOPY
    #undef MFMAS
    #undef XLOAD
    #undef XWRITE
}

extern "C" void kernel_launch(void* const* d_in, const int* in_sizes, int n_in,
                              void* d_out, int out_size, void* d_ws, size_t ws_size,
                              hipStream_t stream) {
    const float* x  = (const float*)d_in[0];
    const float* w1 = (const float*)d_in[1];
    const float* b1 = (const float*)d_in[2];
    const float* w2 = (const float*)d_in[3];
    const float* b2 = (const float*)d_in[4];
    float* out = (float*)d_out;

    bf16* w1c = (bf16*)d_ws;                     // 294,912 B

    k0a_transform<<<dim3(8, 4), 256, 0, stream>>>(w1, w1c);
    k123_fused<<<dim3(BB * HH), 512, 0, stream>>>(x, w1c, b1, w2, b2, out);
}

// Round 13
// 122.731 us; speedup vs baseline: 3.2793x; 1.0583x over previous
//
#include <hip/hip_runtime.h>

// CARAFE on MI355X. B=4, C=256, H=W=64, CMID=64, NK=100 (s=2, k=5).
// v8 = v7 + (a) phase-2 conv1x1 via MFMA (logits GEMM [100x64]x[64x64], fp32 accum,
//      bf16 inputs; feat stored bf16 [px][ic] stride-72; w2 pre-transformed to the
//      proven phase-1 A-image [kkq][oc112][8ic]); (b) phase-1 LOADX issued before
//      MFMAS (T14: load latency hides under compute instead of draining at barrier).
//      v7 post-mortem: spill fixed (VGPR 100, FETCH 66 MB), k123=55us, all pipes <31%
//      -> barrier/latency-bound; phase-2's 832 fp32 FMA/thread (5.5us serial VALU) is
//      the largest removable serial cost.
// LDS map (115968 B):
//   conv  : xs0@0(15872) xs1@15872 wl0@31744(36864) wl1@68608(36864) fsb@105472(9216 bf16)
//   phase2: ls@31744(25600, alias wl0), red@0(alias xs0), kts@68608(alias wl1)
//   phase3: tiles @0,@21760,@43520 (dead xs/wl0), kts@68608..94208, tB1@94208..115968
//           (spans dead wl1-tail + dead fsb). Tiles 21760 B: [r5][g4][slotSW68][c4] f32.

#define BB 4
#define CC 256
#define HH 64
#define WW 64
#define CMID 64
#define NKCH 100

typedef __bf16 bf16;
typedef __bf16 bf16x8 __attribute__((ext_vector_type(8)));
typedef float f32x4 __attribute__((ext_vector_type(4)));

__device__ __forceinline__ void async_copy16(const void* gsrc, void* ldst) {
    __builtin_amdgcn_global_load_lds(
        (__attribute__((address_space(1))) void*)(void*)gsrc,
        (__attribute__((address_space(3))) void*)ldst, 16, 0, 0);
}

// ---- k0a: w1 -> w1c bf16 [c8][kk][q][oc][8]; block(0,0) also w2 -> w2c [kkq][oc112][8] ----
__global__ void k0a_transform(const float* __restrict__ w1, const float* __restrict__ w2,
                              bf16* __restrict__ w1c, bf16* __restrict__ w2c) {
    int c8 = blockIdx.x;          // 0..7
    int oq = blockIdx.y;          // 0..3
    int tid = threadIdx.x;
    __shared__ __align__(16) float wf[16 * 300];

    for (int i = tid; i < 16 * 72; i += 256) {
        int o = i / 72, r = i % 72;
        *(float4*)&wf[o * 300 + r * 4] =
            *(const float4*)&w1[(size_t)(oq * 16 + o) * 2304 + c8 * 288 + r * 4];
    }
    __syncthreads();

    for (int t = tid; t < 576; t += 256) {
        int o = t & 15, q = (t >> 4) & 3, kk = t >> 6;
        union { bf16 h[8]; uint4 u; } v;
        #pragma unroll
        for (int i8 = 0; i8 < 8; ++i8)
            v.h[i8] = (bf16)wf[o * 300 + (q * 8 + i8) * 9 + kk];
        *(uint4*)&w1c[(size_t)((((c8 * 9 + kk) * 4 + q) * 64) + oq * 16 + o) * 8] = v.u;
    }

    if (c8 == 0 && oq == 0) {     // w2c: A-image for the logits GEMM (oc padded to 112)
        for (int i = tid; i < 7168; i += 256) {
            int i8 = i & 7;
            int oc = (i >> 3) % 112;
            int kq = (i >> 3) / 112;          // kk*4+q, 0..7
            int ic = (kq >> 2) * 32 + (kq & 3) * 8 + i8;
            w2c[i] = (oc < NKCH) ? (bf16)w2[oc * 64 + ic] : (bf16)0.f;
        }
    }
}

// ---------------- k123: fused conv3x3+relu + conv1x1+softmax + reassembly ----------------
__global__ __launch_bounds__(512) void k123_fused(const float* __restrict__ x,
        const bf16* __restrict__ w1c, const bf16* __restrict__ w2c,
        const float* __restrict__ b1, const float* __restrict__ b2,
        float* __restrict__ out) {
    int bh = blockIdx.x;
    int b = bh >> 6, h = bh & 63;
    int tid = threadIdx.x;
    int lane = tid & 63, wid = tid >> 6;
    int l15 = lane & 15, quad = lane >> 4;
    int mhalf = wid & 1, nq = wid >> 1;

    __shared__ __align__(16) char smem[115968];
    bf16*  xs0  = (bf16*)smem;
    bf16*  xs1  = (bf16*)(smem + 15872);
    bf16*  wl0  = (bf16*)(smem + 31744);
    bf16*  wl1  = (bf16*)(smem + 68608);
    bf16*  fsb  = (bf16*)(smem + 105472);        // [px64][ic] stride 72 bf16, 9216 B
    float* ls   = (float*)(smem + 31744);        // alias wl0 (25600 <= 36864)
    float* kts  = (float*)(smem + 68608);        // alias wl1 (25600 <= 36864)
    float* red  = (float*)smem;                  // alias xs0 (4096)

    const float* xb = x + (size_t)b * (CC * HH * WW);

    // ---- phase 1: conv3x3 (256->64) + relu, 2-phase pipelined MFMA ----
    int ppp[6], rrr[6];
    bool vmask[6];
    #pragma unroll
    for (int j = 0; j < 6; ++j) {
        int task = wid + j * 8;
        ppp[j] = task & 15;
        rrr[j] = task >> 4;
        int hr = h - 1 + rrr[j];
        vmask[j] = (hr >= 0 && hr < HH);
    }

    float fA0[6], fA1[6], fB0[6], fB1[6];
    #define LOADX(C8, F0, F1)                                                    \
        _Pragma("unroll")                                                        \
        for (int j = 0; j < 6; ++j) {                                            \
            if (vmask[j]) {                                                      \
                const float* src = xb + ((size_t)((C8) * 32 + 2 * ppp[j]) * (HH * WW)) \
                                 + (h - 1 + rrr[j]) * WW + lane;                 \
                F0[j] = src[0]; F1[j] = src[HH * WW];                            \
            }                                                                    \
        }
    #define WRITEB(F0, F1, XSDST)                                                \
        _Pragma("unroll")                                                        \
        for (int j = 0; j < 6; ++j) {                                            \
            if (vmask[j]) {                                                      \
                union { bf16 hh[2]; unsigned u; } cv;                            \
                cv.hh[0] = (bf16)F0[j]; cv.hh[1] = (bf16)F1[j];                  \
                *(unsigned*)&(XSDST)[(rrr[j] * 66 + 1 + lane) * 40 + 2 * ppp[j]] = cv.u; \
            }                                                                    \
        }
    #define ACOPY(C8, WDST)                                                      \
        for (int t = wid; t < 36; t += 8)                                        \
            async_copy16(w1c + ((((C8) * 36 + t) << 9) + lane * 8), (void*)&(WDST)[t << 9]);
    #define MFMAS(XSRC, WSRC)                                                    \
        _Pragma("unroll")                                                        \
        for (int kk = 0; kk < 9; ++kk) {                                         \
            int r3 = kk / 3, kw = kk % 3;                                        \
            bf16x8 a0 = *(const bf16x8*)&(WSRC)[((kk * 4 + quad) * 64 + mhalf * 32 + l15) * 8]; \
            bf16x8 a1 = *(const bf16x8*)&(WSRC)[((kk * 4 + quad) * 64 + mhalf * 32 + 16 + l15) * 8]; \
            bf16x8 xv = *(const bf16x8*)&(XSRC)[(r3 * 66 + nq * 16 + l15 + kw) * 40 + quad * 8]; \
            acc0 = __builtin_amdgcn_mfma_f32_16x16x32_bf16(a0, xv, acc0, 0, 0, 0); \
            acc1 = __builtin_amdgcn_mfma_f32_16x16x32_bf16(a1, xv, acc1, 0, 0, 0); \
        }

    for (int i = tid; i < 7936; i += 512) { xs0[i] = (bf16)0.f; xs1[i] = (bf16)0.f; }
    LOADX(0, fA0, fA1)
    ACOPY(0, wl0)
    __syncthreads();
    WRITEB(fA0, fA1, xs0)
    LOADX(1, fB0, fB1)
    __syncthreads();

    f32x4 acc0 = {0.f, 0.f, 0.f, 0.f}, acc1 = {0.f, 0.f, 0.f, 0.f};

    for (int c8 = 0; c8 < 8; c8 += 2) {
        // even: compute buf0; loads for (c8+2) issued BEFORE MFMAS so they land under it
        ACOPY(c8 + 1, wl1)
        if (c8 < 6) { LOADX(c8 + 2, fA0, fA1) }
        MFMAS(xs0, wl0)
        WRITEB(fB0, fB1, xs1)
        __syncthreads();
        // odd: compute buf1
        if (c8 < 6) { ACOPY(c8 + 2, wl0) }
        if (c8 < 6) { LOADX(c8 + 3, fB0, fB1) }
        MFMAS(xs1, wl1)
        if (c8 < 6) { WRITEB(fA0, fA1, xs0) }
        __syncthreads();
    }

    // conv epilogue: bias+relu -> fsb bf16 [px][ic] stride 72
    int px = nq * 16 + l15;
    #pragma unroll
    for (int mi = 0; mi < 2; ++mi) {
        int oc0 = mhalf * 32 + mi * 16 + quad * 4;
        float4 bv = *(const float4*)&b1[oc0];
        f32x4 v = mi ? acc1 : acc0;
        union { bf16 hh[4]; unsigned long long u; } o;
        o.hh[0] = (bf16)fmaxf(v[0] + bv.x, 0.f);
        o.hh[1] = (bf16)fmaxf(v[1] + bv.y, 0.f);
        o.hh[2] = (bf16)fmaxf(v[2] + bv.z, 0.f);
        o.hh[3] = (bf16)fmaxf(v[3] + bv.w, 0.f);
        *(unsigned long long*)&fsb[px * 72 + oc0] = o.u;
    }
    __syncthreads();

    // ---- phase-3 identities + T14 pre-issue of pair-0 x tiles ----
    int t8 = tid & 255, h2 = tid >> 8;
    int w3 = t8 & 63, cg3 = t8 >> 6;
    #define XLOAD(P, V)                                                          \
        _Pragma("unroll")                                                        \
        for (int k = 0; k < 5; ++k) {                                            \
            int idx = t8 + k * 256;                                              \
            int u = idx & 15, cc = (idx >> 4) & 15, rr = idx >> 8;               \
            int hr = h - 2 + rr;                                                 \
            V[k] = make_float4(0.f, 0.f, 0.f, 0.f);                              \
            if (hr >= 0 && hr < HH)                                              \
                V[k] = *(const float4*)&x[(((size_t)b * CC + (2 * (P) + h2) * 16 + cc) * HH + hr) * WW + 4 * u]; \
        }
    #define XWRITE(V, TB)                                                        \
        _Pragma("unroll")                                                        \
        for (int k = 0; k < 5; ++k) {                                            \
            int idx = t8 + k * 256;                                              \
            int u = idx & 15, cc = (idx >> 4) & 15, rr = idx >> 8;               \
            int bse = (rr * 4 + (cc >> 2)) * 68;                                 \
            int c = cc & 3;                                                      \
            _Pragma("unroll")                                                    \
            for (int j = 0; j < 4; ++j) {                                        \
                int s = 2 + 4 * u + j;                                           \
                int sw = s ^ ((s >> 3) & 7);                                     \
                (TB)[(bse + sw) * 4 + c] = ((const float*)&V[k])[j];             \
            }                                                                    \
        }
    float4 xst[5];
    XLOAD(0, xst)

    // ---- phase 2a: conv1x1 logits via MFMA. A=w2c (proven phase-1 A-image), B=fsb.
    //      Waves 0..6 each own one 16-oc tile (112 padded); D -> ls[oc][px] fp32.
    if (wid < 7) {
        f32x4 lacc0 = {0.f,0.f,0.f,0.f}, lacc1 = {0.f,0.f,0.f,0.f};
        f32x4 lacc2 = {0.f,0.f,0.f,0.f}, lacc3 = {0.f,0.f,0.f,0.f};
        #pragma unroll
        for (int kk = 0; kk < 2; ++kk) {
            bf16x8 a = *(const bf16x8*)&w2c[(((kk * 4 + quad) * 112) + wid * 16 + l15) * 8];
            bf16x8 bf0 = *(const bf16x8*)&fsb[( 0 + l15) * 72 + kk * 32 + quad * 8];
            bf16x8 bf1 = *(const bf16x8*)&fsb[(16 + l15) * 72 + kk * 32 + quad * 8];
            bf16x8 bf2 = *(const bf16x8*)&fsb[(32 + l15) * 72 + kk * 32 + quad * 8];
            bf16x8 bf3 = *(const bf16x8*)&fsb[(48 + l15) * 72 + kk * 32 + quad * 8];
            lacc0 = __builtin_amdgcn_mfma_f32_16x16x32_bf16(a, bf0, lacc0, 0, 0, 0);
            lacc1 = __builtin_amdgcn_mfma_f32_16x16x32_bf16(a, bf1, lacc1, 0, 0, 0);
            lacc2 = __builtin_amdgcn_mfma_f32_16x16x32_bf16(a, bf2, lacc2, 0, 0, 0);
            lacc3 = __builtin_amdgcn_mfma_f32_16x16x32_bf16(a, bf3, lacc3, 0, 0, 0);
        }
        f32x4 laccs[4] = {lacc0, lacc1, lacc2, lacc3};
        #pragma unroll
        for (int nt = 0; nt < 4; ++nt)
            #pragma unroll
            for (int j = 0; j < 4; ++j) {
                int oc = wid * 16 + quad * 4 + j;     // D row = oc, col(l15) = px
                if (oc < NKCH) ls[oc * 64 + nt * 16 + l15] = laccs[nt][j];
            }
    }
    __syncthreads();

    // ---- phase 2b: softmax over FULL 100-channel dim (reads ls) ----
    int w = lane;
    int g = wid, s2 = g & 3, ihalf = g >> 2;
    int i0 = ihalf ? 13 : 0;

    float lg[13];
    #pragma unroll
    for (int ii = 0; ii < 13; ++ii) {
        int idx = i0 + ii;
        bool act = (idx < 25);
        int oc = s2 * 25 + (act ? idx : 0);
        lg[ii] = act ? (ls[oc * 64 + w] + b2[oc]) : -1e30f;
    }

    float m = -1e30f;
    #pragma unroll
    for (int ii = 0; ii < 13; ++ii) m = fmaxf(m, lg[ii]);
    red[g * 64 + w] = m;
    __syncthreads();
    m = fmaxf(fmaxf(fmaxf(red[0 * 64 + w], red[1 * 64 + w]),
                    fmaxf(red[2 * 64 + w], red[3 * 64 + w])),
              fmaxf(fmaxf(red[4 * 64 + w], red[5 * 64 + w]),
                    fmaxf(red[6 * 64 + w], red[7 * 64 + w])));
    float ssum = 0.f;
    #pragma unroll
    for (int ii = 0; ii < 13; ++ii) { lg[ii] = __expf(lg[ii] - m); ssum += lg[ii]; }
    red[512 + g * 64 + w] = ssum;
    __syncthreads();
    ssum = ((red[512 + 0 * 64 + w] + red[512 + 1 * 64 + w]) +
            (red[512 + 2 * 64 + w] + red[512 + 3 * 64 + w])) +
           ((red[512 + 4 * 64 + w] + red[512 + 5 * 64 + w]) +
            (red[512 + 6 * 64 + w] + red[512 + 7 * 64 + w]));
    float inv = 1.f / ssum;
    #pragma unroll
    for (int ii = 0; ii < 13; ++ii)
        if (i0 + ii < 25) kts[((i0 + ii) * 64 + w) * 4 + s2] = lg[ii] * inv;
    __syncthreads();   // kts visible; red/ls/xs/wl/fsb now dead

    // ---- phase 3: reassembly + pixel shuffle (unchanged from v7) ----
    #pragma unroll
    for (int reg = 0; reg < 4; ++reg) {
        const int tb = (reg == 0) ? 0 : (reg == 1) ? 21760 : (reg == 2) ? 43520 : 94208;
        if (tid < 320) {
            int c = tid & 3, q = (tid >> 2) & 3, rg = tid >> 4;
            int slot = (q < 2) ? q : (q + 64);
            ((float*)(smem + tb))[(rg * 68 + slot) * 4 + c] = 0.f;
        }
    }

    float* tb0 = (float*)(smem + (h2 ? 21760 : 0));
    float* tb1 = (float*)(smem + (h2 ? 94208 : 43520));

    int swk[5];
    #pragma unroll
    for (int kw = 0; kw < 5; ++kw) {
        int s = w3 + kw;
        swk[kw] = s ^ ((s >> 3) & 7);
    }

    XWRITE(xst, tb0)
    __syncthreads();

    for (int p = 0; p < 8; ++p) {
        if (p < 7) { XLOAD(p + 1, xst) }
        float* T = (p & 1) ? tb1 : tb0;
        f32x4 a0 = {0.f,0.f,0.f,0.f}, a1 = {0.f,0.f,0.f,0.f};
        f32x4 a2 = {0.f,0.f,0.f,0.f}, a3 = {0.f,0.f,0.f,0.f};
        #pragma unroll
        for (int r = 0; r < 5; ++r) {
            #pragma unroll
            for (int kw = 0; kw < 5; ++kw) {
                f32x4 kvv = *(const f32x4*)&kts[((r * 5 + kw) * 64 + w3) * 4];
                f32x4 xv = *(const f32x4*)&T[((r * 4 + cg3) * 68 + swk[kw]) * 4];
                a0 += kvv.x * xv;
                a1 += kvv.y * xv;
                a2 += kvv.z * xv;
                a3 += kvv.w * xv;
            }
        }
        int cq = (2 * p + h2) * 4 + cg3;
        f32x4 accs[4] = {a0, a1, a2, a3};
        #pragma unroll
        for (int s = 0; s < 4; ++s) {
            size_t base = (((size_t)b * 256 + s * 64 + cq) * 128 + 2 * h) * 128 + 2 * w3;
            *(float2*)&out[base]       = make_float2(accs[s][0], accs[s][1]);
            *(float2*)&out[base + 128] = make_float2(accs[s][2], accs[s][3]);
        }
        if (p < 7) {
            float* Tnext = (p & 1) ? tb0 : tb1;
            XWRITE(xst, Tnext)
        }
        __syncthreads();
    }
    #undef LOADX
    #undef WRITEB
    #undef ACOPY
    #undef MFMAS
    #undef XLOAD
    #undef XWRITE
}

extern "C" void kernel_launch(void* const* d_in, const int* in_sizes, int n_in,
                              void* d_out, int out_size, void* d_ws, size_t ws_size,
                              hipStream_t stream) {
    const float* x  = (const float*)d_in[0];
    const float* w1 = (const float*)d_in[1];
    const float* b1 = (const float*)d_in[2];
    const float* w2 = (const float*)d_in[3];
    const float* b2 = (const float*)d_in[4];
    float* out = (float*)d_out;

    char* wsb = (char*)d_ws;
    bf16* w1c = (bf16*)wsb;                      // 294,912 B
    bf16* w2c = (bf16*)(wsb + 294912);           // 14,336 B

    k0a_transform<<<dim3(8, 4), 256, 0, stream>>>(w1, w2, w1c, w2c);
    k123_fused<<<dim3(BB * HH), 512, 0, stream>>>(x, w1c, w2c, b1, b2, out);
}

// Round 14
// 121.945 us; speedup vs baseline: 3.3004x; 1.0064x over previous
//
#include <hip/hip_runtime.h>

// CARAFE on MI355X. B=4, C=256, H=W=64, CMID=64, NK=100 (s=2, k=5).
// v9 = v8 + (a) xs layout [r][g4][66][8ic]: WRITEB becomes contiguous ds_write_b128
//      (was 4B scalar @ stride 80B = 8-way bank conflict, 3.25M conflict cycles ~5us)
//      and MFMA B-reads become contiguous b128 (conflict-free); (b) phase-2/3 barriers
//      -> lgkmcnt-only raw barriers (out-stores + x-prefetch stay in flight; the
//      compiler's vmcnt(0)-at-__syncthreads was draining 32KB of stores per phase-3
//      iter and killing the XLOAD prefetch across phase-2).
// LDS map (131584 B):
//   conv  : xs0@0(12800) xs1@12800 wl0@25600(36864) wl1@62464(36864) fsb@99328(9216)
//   phase2: ls@25600(alias wl0), red@0(alias xs0), kts@62464(25600, alias wl1)
//   phase3: tiles @0,@21760 (dead xs/wl0-head) and @88064,@109824 (dead wl1-tail/fsb/new);
//           kts@62464..88064 untouched. Tiles 21760 B: [r5][g4][slotSW68][c4] f32.

#define BB 4
#define CC 256
#define HH 64
#define WW 64
#define CMID 64
#define NKCH 100

typedef __bf16 bf16;
typedef __bf16 bf16x8 __attribute__((ext_vector_type(8)));
typedef float f32x4 __attribute__((ext_vector_type(4)));

// lgkmcnt-only barrier: orders LDS ops; leaves global stores/loads in flight.
#define BAR_LGKM() asm volatile("s_waitcnt lgkmcnt(0)\n\ts_barrier" ::: "memory")

__device__ __forceinline__ void async_copy16(const void* gsrc, void* ldst) {
    __builtin_amdgcn_global_load_lds(
        (__attribute__((address_space(1))) void*)(void*)gsrc,
        (__attribute__((address_space(3))) void*)ldst, 16, 0, 0);
}

// ---- k0a: w1 -> w1c bf16 [c8][kk][q][oc][8]; block(0,0) also w2 -> w2c [kkq][oc112][8] ----
__global__ void k0a_transform(const float* __restrict__ w1, const float* __restrict__ w2,
                              bf16* __restrict__ w1c, bf16* __restrict__ w2c) {
    int c8 = blockIdx.x;          // 0..7
    int oq = blockIdx.y;          // 0..3
    int tid = threadIdx.x;
    __shared__ __align__(16) float wf[16 * 300];

    for (int i = tid; i < 16 * 72; i += 256) {
        int o = i / 72, r = i % 72;
        *(float4*)&wf[o * 300 + r * 4] =
            *(const float4*)&w1[(size_t)(oq * 16 + o) * 2304 + c8 * 288 + r * 4];
    }
    __syncthreads();

    for (int t = tid; t < 576; t += 256) {
        int o = t & 15, q = (t >> 4) & 3, kk = t >> 6;
        union { bf16 h[8]; uint4 u; } v;
        #pragma unroll
        for (int i8 = 0; i8 < 8; ++i8)
            v.h[i8] = (bf16)wf[o * 300 + (q * 8 + i8) * 9 + kk];
        *(uint4*)&w1c[(size_t)((((c8 * 9 + kk) * 4 + q) * 64) + oq * 16 + o) * 8] = v.u;
    }

    if (c8 == 0 && oq == 0) {     // w2c: A-image for the logits GEMM (oc padded to 112)
        for (int i = tid; i < 7168; i += 256) {
            int i8 = i & 7;
            int oc = (i >> 3) % 112;
            int kq = (i >> 3) / 112;          // kk*4+q, 0..7
            int ic = (kq >> 2) * 32 + (kq & 3) * 8 + i8;
            w2c[i] = (oc < NKCH) ? (bf16)w2[oc * 64 + ic] : (bf16)0.f;
        }
    }
}

// ---------------- k123: fused conv3x3+relu + conv1x1+softmax + reassembly ----------------
__global__ __launch_bounds__(512) void k123_fused(const float* __restrict__ x,
        const bf16* __restrict__ w1c, const bf16* __restrict__ w2c,
        const float* __restrict__ b1, const float* __restrict__ b2,
        float* __restrict__ out) {
    int bh = blockIdx.x;
    int b = bh >> 6, h = bh & 63;
    int tid = threadIdx.x;
    int lane = tid & 63, wid = tid >> 6;
    int l15 = lane & 15, quad = lane >> 4;
    int mhalf = wid & 1, nq = wid >> 1;

    __shared__ __align__(16) char smem[131584];
    bf16*  xs0  = (bf16*)smem;                   // [r3][g4][66][8] = 12672 B (pad 12800)
    bf16*  xs1  = (bf16*)(smem + 12800);
    bf16*  wl0  = (bf16*)(smem + 25600);
    bf16*  wl1  = (bf16*)(smem + 62464);
    bf16*  fsb  = (bf16*)(smem + 99328);         // [px64][ic] stride 72 bf16, 9216 B
    float* ls   = (float*)(smem + 25600);        // alias wl0 (25600 <= 36864)
    float* kts  = (float*)(smem + 62464);        // alias wl1 (25600 <= 36864)
    float* red  = (float*)smem;                  // alias xs0 (4096)

    const float* xb = x + (size_t)b * (CC * HH * WW);

    // ---- phase 1: conv3x3 (256->64) + relu, 2-phase pipelined MFMA ----
    // B-stage: 12 tasks (r x g), each = 8 coalesced plane-loads + 1 contiguous b128 write.
    // task A = wid (g0, r0); task B = wid+8 (g0, r=2), valid for wid<4.
    int g0 = wid & 3, r0 = wid >> 2;
    bool tv1 = (wid < 4);
    int hr0 = h - 1 + r0;
    int hr1 = h + 1;
    bool vm0 = (hr0 >= 0 && hr0 < HH);
    bool vm1 = (hr1 < HH);

    float fA[16], fB[16];
    #define LOADX(C8, F)                                                          \
        {                                                                         \
            if (vm0) {                                                            \
                const float* s0 = xb + ((size_t)((C8) * 32 + g0 * 8) * (HH * WW)) \
                                 + hr0 * WW + lane;                               \
                _Pragma("unroll")                                                 \
                for (int i = 0; i < 8; ++i) F[i] = s0[(size_t)i * (HH * WW)];     \
            }                                                                     \
            if (tv1 && vm1) {                                                     \
                const float* s1 = xb + ((size_t)((C8) * 32 + g0 * 8) * (HH * WW)) \
                                 + hr1 * WW + lane;                               \
                _Pragma("unroll")                                                 \
                for (int i = 0; i < 8; ++i) F[8 + i] = s1[(size_t)i * (HH * WW)]; \
            }                                                                     \
        }
    #define WRITEB(F, XSDST)                                                      \
        {                                                                         \
            if (vm0) {                                                            \
                union { bf16 hh[8]; uint4 u; } cv;                                \
                _Pragma("unroll")                                                 \
                for (int i = 0; i < 8; ++i) cv.hh[i] = (bf16)F[i];                \
                *(uint4*)&(XSDST)[((r0 * 4 + g0) * 66 + 1 + lane) * 8] = cv.u;    \
            }                                                                     \
            if (tv1 && vm1) {                                                     \
                union { bf16 hh[8]; uint4 u; } cv;                                \
                _Pragma("unroll")                                                 \
                for (int i = 0; i < 8; ++i) cv.hh[i] = (bf16)F[8 + i];            \
                *(uint4*)&(XSDST)[((2 * 4 + g0) * 66 + 1 + lane) * 8] = cv.u;     \
            }                                                                     \
        }
    #define ACOPY(C8, WDST)                                                       \
        for (int t = wid; t < 36; t += 8)                                         \
            async_copy16(w1c + ((((C8) * 36 + t) << 9) + lane * 8), (void*)&(WDST)[t << 9]);
    #define MFMAS(XSRC, WSRC)                                                     \
        _Pragma("unroll")                                                         \
        for (int kk = 0; kk < 9; ++kk) {                                          \
            int r3 = kk / 3, kw = kk % 3;                                         \
            bf16x8 a0 = *(const bf16x8*)&(WSRC)[((kk * 4 + quad) * 64 + mhalf * 32 + l15) * 8]; \
            bf16x8 a1 = *(const bf16x8*)&(WSRC)[((kk * 4 + quad) * 64 + mhalf * 32 + 16 + l15) * 8]; \
            bf16x8 xv = *(const bf16x8*)&(XSRC)[((r3 * 4 + quad) * 66 + nq * 16 + l15 + kw) * 8]; \
            acc0 = __builtin_amdgcn_mfma_f32_16x16x32_bf16(a0, xv, acc0, 0, 0, 0); \
            acc1 = __builtin_amdgcn_mfma_f32_16x16x32_bf16(a1, xv, acc1, 0, 0, 0); \
        }

    for (int i = tid; i < 6336; i += 512) { xs0[i] = (bf16)0.f; xs1[i] = (bf16)0.f; }
    LOADX(0, fA)
    ACOPY(0, wl0)
    __syncthreads();
    WRITEB(fA, xs0)
    LOADX(1, fB)
    __syncthreads();

    f32x4 acc0 = {0.f, 0.f, 0.f, 0.f}, acc1 = {0.f, 0.f, 0.f, 0.f};

    for (int c8 = 0; c8 < 8; c8 += 2) {
        ACOPY(c8 + 1, wl1)
        if (c8 < 6) { LOADX(c8 + 2, fA) }
        MFMAS(xs0, wl0)
        WRITEB(fB, xs1)
        __syncthreads();
        if (c8 < 6) { ACOPY(c8 + 2, wl0) }
        if (c8 < 6) { LOADX(c8 + 3, fB) }
        MFMAS(xs1, wl1)
        if (c8 < 6) { WRITEB(fA, xs0) }
        __syncthreads();
    }

    // conv epilogue: bias+relu -> fsb bf16 [px][ic] stride 72
    int px = nq * 16 + l15;
    #pragma unroll
    for (int mi = 0; mi < 2; ++mi) {
        int oc0 = mhalf * 32 + mi * 16 + quad * 4;
        float4 bv = *(const float4*)&b1[oc0];
        f32x4 v = mi ? acc1 : acc0;
        union { bf16 hh[4]; unsigned long long u; } o;
        o.hh[0] = (bf16)fmaxf(v[0] + bv.x, 0.f);
        o.hh[1] = (bf16)fmaxf(v[1] + bv.y, 0.f);
        o.hh[2] = (bf16)fmaxf(v[2] + bv.z, 0.f);
        o.hh[3] = (bf16)fmaxf(v[3] + bv.w, 0.f);
        *(unsigned long long*)&fsb[px * 72 + oc0] = o.u;
    }
    __syncthreads();

    // ---- phase-3 identities + T14 pre-issue of pair-0 x tiles ----
    int t8 = tid & 255, h2 = tid >> 8;
    int w3 = t8 & 63, cg3 = t8 >> 6;
    #define XLOAD(P, V)                                                          \
        _Pragma("unroll")                                                        \
        for (int k = 0; k < 5; ++k) {                                            \
            int idx = t8 + k * 256;                                              \
            int u = idx & 15, cc = (idx >> 4) & 15, rr = idx >> 8;               \
            int hr = h - 2 + rr;                                                 \
            V[k] = make_float4(0.f, 0.f, 0.f, 0.f);                              \
            if (hr >= 0 && hr < HH)                                              \
                V[k] = *(const float4*)&x[(((size_t)b * CC + (2 * (P) + h2) * 16 + cc) * HH + hr) * WW + 4 * u]; \
        }
    #define XWRITE(V, TB)                                                        \
        _Pragma("unroll")                                                        \
        for (int k = 0; k < 5; ++k) {                                            \
            int idx = t8 + k * 256;                                              \
            int u = idx & 15, cc = (idx >> 4) & 15, rr = idx >> 8;               \
            int bse = (rr * 4 + (cc >> 2)) * 68;                                 \
            int c = cc & 3;                                                      \
            _Pragma("unroll")                                                    \
            for (int j = 0; j < 4; ++j) {                                        \
                int s = 2 + 4 * u + j;                                           \
                int sw = s ^ ((s >> 3) & 7);                                     \
                (TB)[(bse + sw) * 4 + c] = ((const float*)&V[k])[j];             \
            }                                                                    \
        }
    float4 xst[5];
    XLOAD(0, xst)

    // ---- phase 2a: conv1x1 logits via MFMA. A=w2c, B=fsb. D -> ls[oc][px] fp32 ----
    if (wid < 7) {
        f32x4 lacc0 = {0.f,0.f,0.f,0.f}, lacc1 = {0.f,0.f,0.f,0.f};
        f32x4 lacc2 = {0.f,0.f,0.f,0.f}, lacc3 = {0.f,0.f,0.f,0.f};
        #pragma unroll
        for (int kk = 0; kk < 2; ++kk) {
            bf16x8 a = *(const bf16x8*)&w2c[(((kk * 4 + quad) * 112) + wid * 16 + l15) * 8];
            bf16x8 bf0 = *(const bf16x8*)&fsb[( 0 + l15) * 72 + kk * 32 + quad * 8];
            bf16x8 bf1 = *(const bf16x8*)&fsb[(16 + l15) * 72 + kk * 32 + quad * 8];
            bf16x8 bf2 = *(const bf16x8*)&fsb[(32 + l15) * 72 + kk * 32 + quad * 8];
            bf16x8 bf3 = *(const bf16x8*)&fsb[(48 + l15) * 72 + kk * 32 + quad * 8];
            lacc0 = __builtin_amdgcn_mfma_f32_16x16x32_bf16(a, bf0, lacc0, 0, 0, 0);
            lacc1 = __builtin_amdgcn_mfma_f32_16x16x32_bf16(a, bf1, lacc1, 0, 0, 0);
            lacc2 = __builtin_amdgcn_mfma_f32_16x16x32_bf16(a, bf2, lacc2, 0, 0, 0);
            lacc3 = __builtin_amdgcn_mfma_f32_16x16x32_bf16(a, bf3, lacc3, 0, 0, 0);
        }
        f32x4 laccs[4] = {lacc0, lacc1, lacc2, lacc3};
        #pragma unroll
        for (int nt = 0; nt < 4; ++nt)
            #pragma unroll
            for (int j = 0; j < 4; ++j) {
                int oc = wid * 16 + quad * 4 + j;     // D row = oc, col(l15) = px
                if (oc < NKCH) ls[oc * 64 + nt * 16 + l15] = laccs[nt][j];
            }
    }
    BAR_LGKM();   // LDS-only ordering; XLOAD(0) stays in flight

    // ---- phase 2b: softmax over FULL 100-channel dim (reads ls) ----
    int w = lane;
    int g = wid, s2 = g & 3, ihalf = g >> 2;
    int i0 = ihalf ? 13 : 0;

    float lg[13];
    #pragma unroll
    for (int ii = 0; ii < 13; ++ii) {
        int idx = i0 + ii;
        bool act = (idx < 25);
        int oc = s2 * 25 + (act ? idx : 0);
        lg[ii] = act ? (ls[oc * 64 + w] + b2[oc]) : -1e30f;
    }

    float m = -1e30f;
    #pragma unroll
    for (int ii = 0; ii < 13; ++ii) m = fmaxf(m, lg[ii]);
    red[g * 64 + w] = m;
    BAR_LGKM();
    m = fmaxf(fmaxf(fmaxf(red[0 * 64 + w], red[1 * 64 + w]),
                    fmaxf(red[2 * 64 + w], red[3 * 64 + w])),
              fmaxf(fmaxf(red[4 * 64 + w], red[5 * 64 + w]),
                    fmaxf(red[6 * 64 + w], red[7 * 64 + w])));
    float ssum = 0.f;
    #pragma unroll
    for (int ii = 0; ii < 13; ++ii) { lg[ii] = __expf(lg[ii] - m); ssum += lg[ii]; }
    red[512 + g * 64 + w] = ssum;
    BAR_LGKM();
    ssum = ((red[512 + 0 * 64 + w] + red[512 + 1 * 64 + w]) +
            (red[512 + 2 * 64 + w] + red[512 + 3 * 64 + w])) +
           ((red[512 + 4 * 64 + w] + red[512 + 5 * 64 + w]) +
            (red[512 + 6 * 64 + w] + red[512 + 7 * 64 + w]));
    float inv = 1.f / ssum;
    #pragma unroll
    for (int ii = 0; ii < 13; ++ii)
        if (i0 + ii < 25) kts[((i0 + ii) * 64 + w) * 4 + s2] = lg[ii] * inv;
    BAR_LGKM();   // kts visible; red/ls/xs/wl/fsb now dead

    // ---- phase 3: reassembly + pixel shuffle, 2 chunks/iter, double-buffered tiles ----
    // zero border slots (0,1,66,67) of all 4 tile regions once
    #pragma unroll
    for (int reg = 0; reg < 4; ++reg) {
        const int tb = (reg == 0) ? 0 : (reg == 1) ? 21760 : (reg == 2) ? 88064 : 109824;
        if (tid < 320) {
            int c = tid & 3, q = (tid >> 2) & 3, rg = tid >> 4;
            int slot = (q < 2) ? q : (q + 64);
            ((float*)(smem + tb))[(rg * 68 + slot) * 4 + c] = 0.f;
        }
    }

    float* tb0 = (float*)(smem + (h2 ? 21760 : 0));
    float* tb1 = (float*)(smem + (h2 ? 109824 : 88064));

    int swk[5];
    #pragma unroll
    for (int kw = 0; kw < 5; ++kw) {
        int s = w3 + kw;
        swk[kw] = s ^ ((s >> 3) & 7);
    }

    XWRITE(xst, tb0)
    BAR_LGKM();

    for (int p = 0; p < 8; ++p) {
        if (p < 7) { XLOAD(p + 1, xst) }       // T14: issue next pair's loads now
        float* T = (p & 1) ? tb1 : tb0;
        f32x4 a0 = {0.f,0.f,0.f,0.f}, a1 = {0.f,0.f,0.f,0.f};
        f32x4 a2 = {0.f,0.f,0.f,0.f}, a3 = {0.f,0.f,0.f,0.f};
        #pragma unroll
        for (int r = 0; r < 5; ++r) {
            #pragma unroll
            for (int kw = 0; kw < 5; ++kw) {
                f32x4 kvv = *(const f32x4*)&kts[((r * 5 + kw) * 64 + w3) * 4];
                f32x4 xv = *(const f32x4*)&T[((r * 4 + cg3) * 68 + swk[kw]) * 4];
                a0 += kvv.x * xv;
                a1 += kvv.y * xv;
                a2 += kvv.z * xv;
                a3 += kvv.w * xv;
            }
        }
        int cq = (2 * p + h2) * 4 + cg3;
        f32x4 accs[4] = {a0, a1, a2, a3};
        #pragma unroll
        for (int s = 0; s < 4; ++s) {
            size_t base = (((size_t)b * 256 + s * 64 + cq) * 128 + 2 * h) * 128 + 2 * w3;
            *(float2*)&out[base]       = make_float2(accs[s][0], accs[s][1]);
            *(float2*)&out[base + 128] = make_float2(accs[s][2], accs[s][3]);
        }
        if (p < 7) {
            float* Tnext = (p & 1) ? tb0 : tb1;
            XWRITE(xst, Tnext)
        }
        BAR_LGKM();   // out-stores stay in flight; kernel-end wait drains them
    }
    #undef LOADX
    #undef WRITEB
    #undef ACOPY
    #undef MFMAS
    #undef XLOAD
    #undef XWRITE
}

extern "C" void kernel_launch(void* const* d_in, const int* in_sizes, int n_in,
                              void* d_out, int out_size, void* d_ws, size_t ws_size,
                              hipStream_t stream) {
    const float* x  = (const float*)d_in[0];
    const float* w1 = (const float*)d_in[1];
    const float* b1 = (const float*)d_in[2];
    const float* w2 = (const float*)d_in[3];
    const float* b2 = (const float*)d_in[4];
    float* out = (float*)d_out;

    char* wsb = (char*)d_ws;
    bf16* w1c = (bf16*)wsb;                      // 294,912 B
    bf16* w2c = (bf16*)(wsb + 294912);           // 14,336 B

    k0a_transform<<<dim3(8, 4), 256, 0, stream>>>(w1, w2, w1c, w2c);
    k123_fused<<<dim3(BB * HH), 512, 0, stream>>>(x, w1c, w2c, b1, b2, out);
}